// Round 4
// baseline (241.368 us; speedup 1.0000x reference)
//
#include <hip/hip_runtime.h>
#include <stdint.h>

#define S_LEN 512
#define I_DIM 28
#define H_DIM 128
#define O_DIM 28
#define BT    16   // batch rows per block

typedef __attribute__((ext_vector_type(8))) short bf16x8;
typedef __attribute__((ext_vector_type(4))) float f32x4;

__device__ __forceinline__ short f2bf(float f) {        // cold paths only
    unsigned u = __float_as_uint(f);
    u = (u + 0x7fffu + ((u >> 16) & 1u)) >> 16;
    return (short)u;
}
__device__ __forceinline__ float bf2f(unsigned short u) {
    return __uint_as_float(((unsigned)u) << 16);
}
__device__ __forceinline__ unsigned cvt_pk(float a, float b) {
    unsigned r;
    asm("v_cvt_pk_bf16_f32 %0, %1, %2" : "=v"(r) : "v"(a), "v"(b));
    return r;
}

__global__ __launch_bounds__(256, 1) void rnn_fused(
    const float* __restrict__ x,
    const float* __restrict__ W_ih, const float* __restrict__ b_ih,
    const float* __restrict__ W_hh, const float* __restrict__ b_hh,
    const float* __restrict__ W_ho, const float* __restrict__ b_ho,
    float* __restrict__ out)
{
    const int tid  = threadIdx.x;
    const int wave = tid >> 6;         // 0..3 -> j-chunk [32w, 32w+32)
    const int lane = tid & 63;
    const int l15  = lane & 15;        // batch row within tile (B-col / A-row slot)
    const int lk   = lane >> 4;        // 0..3 k-group
    const int r0   = blockIdx.x * BT;

    // h exchange: B-fragment per chunk, double-buffered. 8KB
    __shared__ __align__(16) bf16x8 hx[2][4][64];
    // x B-fragment ring (shared by all waves). 8KB
    __shared__ __align__(16) bf16x8 xring[8][64];
    // tanh LUT: idx = round(a*512)+2048, clamped. 16KB
    __shared__ float lut[4096];

    for (int i = tid; i < 4096; i += 256)
        lut[i] = tanhf((float)(i - 2048) * 0.001953125f);

    // ---- stationary A-fragments (swapped form: A = W^T, permuted cols) ----
    // tile T of wave w covers j(m) = 32w + (m>>2)*8 + T*4 + (m&3), m = row slot.
    // A-frag: lane(lk,l15): A[m=l15][k=lk*8+e].
    bf16x8 Ahh[2][4];   // [tile][k-chunk]
    bf16x8 Aih[2];
    float  bias[2][4];  // C-side: m = lk*4+r
    const int jmA = 32 * wave + ((l15 >> 2) << 3) + (l15 & 3);
    #pragma unroll
    for (int T = 0; T < 2; ++T) {
        const int jA = jmA + T * 4;
        #pragma unroll
        for (int kc = 0; kc < 4; ++kc)
            #pragma unroll
            for (int e = 0; e < 8; ++e)
                Ahh[T][kc][e] = f2bf(W_hh[(kc * 32 + lk * 8 + e) * H_DIM + jA]);
        #pragma unroll
        for (int e = 0; e < 8; ++e) {
            int i = lk * 8 + e;
            Aih[T][e] = (i < I_DIM) ? f2bf(W_ih[i * H_DIM + jA]) : (short)0;
        }
        #pragma unroll
        for (int r = 0; r < 4; ++r) {
            int jC = 32 * wave + lk * 8 + T * 4 + r;
            bias[T][r] = b_ih[jC] + b_hh[jC];
        }
    }

    // h0 = 0
    {
        bf16x8 z = {0,0,0,0,0,0,0,0};
        hx[0][wave][lane] = z;
    }

    const bool hasHi = (lk < 3);       // k-group 3: only i=24..27 valid
    const float* xbase = x + (size_t)(r0 + l15) * S_LEN * I_DIM + lk * 8;

    // ---- prologue: wave w stages x frame w ----
    {
        const float* src = xbase + wave * I_DIM;
        float4 lo = *(const float4*)src;
        float4 hi = hasHi ? *(const float4*)(src + 4) : make_float4(0.f,0.f,0.f,0.f);
        union { bf16x8 v; unsigned u[4]; } f;
        f.u[0] = cvt_pk(lo.x, lo.y); f.u[1] = cvt_pk(lo.z, lo.w);
        f.u[2] = cvt_pk(hi.x, hi.y); f.u[3] = cvt_pk(hi.z, hi.w);
        xring[wave][lane] = f.v;
    }
    asm volatile("s_waitcnt lgkmcnt(0)" ::: "memory");
    __builtin_amdgcn_s_barrier();
    asm volatile("" ::: "memory");

    bf16x8 xcur = xring[0][lane];

    // ---- time loop ----
    for (int t4 = 0; t4 < S_LEN; t4 += 4) {
        const int tf = t4 + 4 + wave;            // frame this wave stages
        float4 pf_lo = make_float4(0.f,0.f,0.f,0.f), pf_hi = pf_lo;
        #pragma unroll
        for (int p = 0; p < 4; ++p) {
            const int t = t4 + p;
            const bf16x8* rb = &hx[t & 1][0][0];

            // issue state reads (all 4 chunks) + next x-frag read up front
            bf16x8 b0 = rb[0 * 64 + lane];
            bf16x8 b1 = rb[1 * 64 + lane];
            bf16x8 b2 = rb[2 * 64 + lane];
            bf16x8 b3 = rb[3 * 64 + lane];
            bf16x8 xnext = xring[(t + 1) & 7][lane];

            if (p == 0 && tf < S_LEN) {          // global prefetch for frame tf
                const float* src = xbase + (size_t)tf * I_DIM;
                pf_lo = *(const float4*)src;
                if (hasHi) pf_hi = *(const float4*)(src + 4);
            }

            // 4 accumulator chains (depth 3 each)
            f32x4 a0a = {0.f,0.f,0.f,0.f};
            f32x4 a1a = {0.f,0.f,0.f,0.f};
            f32x4 a0b = {bias[0][0], bias[0][1], bias[0][2], bias[0][3]};
            f32x4 a1b = {bias[1][0], bias[1][1], bias[1][2], bias[1][3]};
            a0a = __builtin_amdgcn_mfma_f32_16x16x32_bf16(Aih[0],    xcur, a0a, 0,0,0);
            a1a = __builtin_amdgcn_mfma_f32_16x16x32_bf16(Aih[1],    xcur, a1a, 0,0,0);
            a0a = __builtin_amdgcn_mfma_f32_16x16x32_bf16(Ahh[0][0], b0,   a0a, 0,0,0);
            a1a = __builtin_amdgcn_mfma_f32_16x16x32_bf16(Ahh[1][0], b0,   a1a, 0,0,0);
            a0a = __builtin_amdgcn_mfma_f32_16x16x32_bf16(Ahh[0][1], b1,   a0a, 0,0,0);
            a1a = __builtin_amdgcn_mfma_f32_16x16x32_bf16(Ahh[1][1], b1,   a1a, 0,0,0);
            a0b = __builtin_amdgcn_mfma_f32_16x16x32_bf16(Ahh[0][2], b2,   a0b, 0,0,0);
            a1b = __builtin_amdgcn_mfma_f32_16x16x32_bf16(Ahh[1][2], b2,   a1b, 0,0,0);
            a0b = __builtin_amdgcn_mfma_f32_16x16x32_bf16(Ahh[0][3], b3,   a0b, 0,0,0);
            a1b = __builtin_amdgcn_mfma_f32_16x16x32_bf16(Ahh[1][3], b3,   a1b, 0,0,0);

            if (p == 2 && tf < S_LEN) {          // late ring write of staged frame
                union { bf16x8 v; unsigned u[4]; } f;
                f.u[0] = cvt_pk(pf_lo.x, pf_lo.y); f.u[1] = cvt_pk(pf_lo.z, pf_lo.w);
                f.u[2] = cvt_pk(pf_hi.x, pf_hi.y); f.u[3] = cvt_pk(pf_hi.z, pf_hi.w);
                xring[tf & 7][lane] = f.v;
            }

            // tanh via LDS LUT: h[e=T*4+r] = tanh(aT[r]); lane-local B-frag!
            float hv[8];
            #pragma unroll
            for (int T = 0; T < 2; ++T) {
                f32x4 sa = (T == 0) ? a0a : a1a;
                f32x4 sb = (T == 0) ? a0b : a1b;
                #pragma unroll
                for (int r = 0; r < 4; ++r) {
                    float s = sa[r] + sb[r];
                    float sc = fmaf(s, 512.0f, 2048.5f);
                    sc = fminf(fmaxf(sc, 0.0f), 4095.0f);
                    hv[T * 4 + r] = lut[(int)sc];
                }
            }
            union { bf16x8 v; unsigned u[4]; } hf;
            hf.u[0] = cvt_pk(hv[0], hv[1]); hf.u[1] = cvt_pk(hv[2], hv[3]);
            hf.u[2] = cvt_pk(hv[4], hv[5]); hf.u[3] = cvt_pk(hv[6], hv[7]);
            hx[(t & 1) ^ 1][wave][lane] = hf.v;

            asm volatile("s_waitcnt lgkmcnt(0)" ::: "memory");
            __builtin_amdgcn_s_barrier();
            asm volatile("" ::: "memory");
            xcur = xnext;
        }
    }

    // ---- epilogue: out = h_512 @ W_ho + b_ho ; h_512 is in hx[0] ----
    // h[b][j] lives at chunk j>>5, lane ((j>>3)&3)*16 + b, halfword j&7
    for (int idx = tid; idx < BT * O_DIM; idx += 256) {
        const int b = idx / O_DIM;
        const int o = idx - b * O_DIM;
        float sum = b_ho[o];
        const unsigned short* hb = (const unsigned short*)&hx[0][0][0];
        #pragma unroll 4
        for (int j = 0; j < H_DIM; ++j) {
            int slot = (j >> 5) * 64 + ((j >> 3) & 3) * 16 + b;
            sum += bf2f(hb[slot * 8 + (j & 7)]) * W_ho[j * O_DIM + o];
        }
        out[(size_t)(r0 + b) * O_DIM + o] = sum;
    }
}

extern "C" void kernel_launch(void* const* d_in, const int* in_sizes, int n_in,
                              void* d_out, int out_size, void* d_ws, size_t ws_size,
                              hipStream_t stream) {
    const float* x    = (const float*)d_in[0];
    const float* W_ih = (const float*)d_in[1];
    const float* b_ih = (const float*)d_in[2];
    const float* W_hh = (const float*)d_in[3];
    const float* b_hh = (const float*)d_in[4];
    const float* W_ho = (const float*)d_in[5];
    const float* b_ho = (const float*)d_in[6];
    const int B = in_sizes[0] / (S_LEN * I_DIM);   // 4096
    rnn_fused<<<B / BT, 256, 0, stream>>>(x, W_ih, b_ih, W_hh, b_hh, W_ho, b_ho,
                                          (float*)d_out);
}